// Round 1
// baseline (761.985 us; speedup 1.0000x reference)
//
#include <hip/hip_runtime.h>

typedef __attribute__((ext_vector_type(4))) float f32x4;
typedef __attribute__((ext_vector_type(16))) float f32x16;
typedef __attribute__((ext_vector_type(8))) short bf16x8;

#define BK 64
#define SROW 72   // LDS row stride in bf16 elems (64 + 8 pad) = 144 B
#define GRID 512
#define NTHR 512

__device__ __forceinline__ unsigned pack_hi(unsigned ua, unsigned ub) {
    // bf16(a) | bf16(b) << 16, truncation rounding
    return (ua >> 16) | (ub & 0xffff0000u);
}

__global__ __launch_bounds__(NTHR, 4)
void mainK(const float* __restrict__ x, float* __restrict__ ws, int nchunks)
{
    __shared__ short ht[128][SROW];
    __shared__ short lt[128][SROW];

    float* wsGh  = ws;            // [128][128]
    float* wsGhl = ws + 16384;    // [128][128]
    float* wsS   = ws + 32768;    // [128]

    const int tid  = threadIdx.x;
    const int lane = tid & 63;
    const int wave = tid >> 6;
    const int c0   = 4 * (tid >> 4);   // column base 0..124
    const int k0   = 2 * (tid & 15);   // row-pair base 0..30

    const int frc = lane & 31;   // row/col within 32x32 tile
    const int frg = lane >> 5;   // k-group

    f32x16 acc[4];
    #pragma unroll
    for (int j = 0; j < 4; ++j)
        #pragma unroll
        for (int r = 0; r < 16; ++r) acc[j][r] = 0.0f;

    float csum[4] = {0.f, 0.f, 0.f, 0.f};

    const bool isGh = (wave < 4);
    const int e0 = 32 * (wave & 3);

    int chunk = blockIdx.x;
    f32x4 v0, v1, v2, v3;
    {
        const float* p = x + (size_t)chunk * (BK * 128) + c0;
        v0 = *(const f32x4*)(p + (size_t)(k0     ) * 128);
        v1 = *(const f32x4*)(p + (size_t)(k0 + 1 ) * 128);
        v2 = *(const f32x4*)(p + (size_t)(k0 + 32) * 128);
        v3 = *(const f32x4*)(p + (size_t)(k0 + 33) * 128);
    }

    while (true) {
        __syncthreads();  // previous iteration's readers done
        #pragma unroll
        for (int i = 0; i < 4; ++i) {
            float a = v0[i], b = v1[i], c = v2[i], d = v3[i];
            csum[i] += (a + b) + (c + d);
            unsigned ua = __float_as_uint(a), ub = __float_as_uint(b);
            unsigned uc = __float_as_uint(c), ud = __float_as_uint(d);
            unsigned la = __float_as_uint(a - __uint_as_float(ua & 0xffff0000u));
            unsigned lb = __float_as_uint(b - __uint_as_float(ub & 0xffff0000u));
            unsigned lc = __float_as_uint(c - __uint_as_float(uc & 0xffff0000u));
            unsigned ld = __float_as_uint(d - __uint_as_float(ud & 0xffff0000u));
            *(unsigned*)&ht[c0 + i][k0     ] = pack_hi(ua, ub);
            *(unsigned*)&ht[c0 + i][k0 + 32] = pack_hi(uc, ud);
            *(unsigned*)&lt[c0 + i][k0     ] = pack_hi(la, lb);
            *(unsigned*)&lt[c0 + i][k0 + 32] = pack_hi(lc, ld);
        }
        __syncthreads();  // writes visible

        const int next = chunk + GRID;
        const bool hasNext = next < nchunks;
        if (hasNext) {  // prefetch next chunk; latency hides under MFMAs
            const float* p = x + (size_t)next * (BK * 128) + c0;
            v0 = *(const f32x4*)(p + (size_t)(k0     ) * 128);
            v1 = *(const f32x4*)(p + (size_t)(k0 + 1 ) * 128);
            v2 = *(const f32x4*)(p + (size_t)(k0 + 32) * 128);
            v3 = *(const f32x4*)(p + (size_t)(k0 + 33) * 128);
        }

        #pragma unroll
        for (int ks = 0; ks < 4; ++ks) {
            const int kb = ks * 16 + 8 * frg;
            if (isGh) {
                bf16x8 f0 = *(const bf16x8*)&ht[ 0 + frc][kb];
                bf16x8 f1 = *(const bf16x8*)&ht[32 + frc][kb];
                bf16x8 f2 = *(const bf16x8*)&ht[64 + frc][kb];
                bf16x8 f3 = *(const bf16x8*)&ht[96 + frc][kb];
                bf16x8 fa = (e0 == 0) ? f0 : (e0 == 32) ? f1 : (e0 == 64) ? f2 : f3;
                acc[0] = __builtin_amdgcn_mfma_f32_32x32x16_bf16(fa, f0, acc[0], 0, 0, 0);
                acc[1] = __builtin_amdgcn_mfma_f32_32x32x16_bf16(fa, f1, acc[1], 0, 0, 0);
                acc[2] = __builtin_amdgcn_mfma_f32_32x32x16_bf16(fa, f2, acc[2], 0, 0, 0);
                acc[3] = __builtin_amdgcn_mfma_f32_32x32x16_bf16(fa, f3, acc[3], 0, 0, 0);
            } else {
                bf16x8 fa = *(const bf16x8*)&ht[e0 + frc][kb];
                bf16x8 f0 = *(const bf16x8*)&lt[ 0 + frc][kb];
                bf16x8 f1 = *(const bf16x8*)&lt[32 + frc][kb];
                bf16x8 f2 = *(const bf16x8*)&lt[64 + frc][kb];
                bf16x8 f3 = *(const bf16x8*)&lt[96 + frc][kb];
                acc[0] = __builtin_amdgcn_mfma_f32_32x32x16_bf16(fa, f0, acc[0], 0, 0, 0);
                acc[1] = __builtin_amdgcn_mfma_f32_32x32x16_bf16(fa, f1, acc[1], 0, 0, 0);
                acc[2] = __builtin_amdgcn_mfma_f32_32x32x16_bf16(fa, f2, acc[2], 0, 0, 0);
                acc[3] = __builtin_amdgcn_mfma_f32_32x32x16_bf16(fa, f3, acc[3], 0, 0, 0);
            }
        }

        if (!hasNext) break;
        chunk = next;
    }

    // write block partials: G = Gh + Ghl + Ghl^T assembled in finish kernel
    float* dst = isGh ? wsGh : wsGhl;
    #pragma unroll
    for (int j = 0; j < 4; ++j)
        #pragma unroll
        for (int r = 0; r < 16; ++r) {
            const int row = e0 + (r & 3) + 8 * (r >> 2) + 4 * frg;  // C/D layout (m74/m101)
            const int col = 32 * j + frc;
            atomicAdd(&dst[row * 128 + col], acc[j][r]);
        }

    // column sums: reduce the 16 threads sharing c0 (same wave, lanes l&15)
    #pragma unroll
    for (int i = 0; i < 4; ++i) {
        float s = csum[i];
        #pragma unroll
        for (int off = 1; off < 16; off <<= 1) s += __shfl_xor(s, off);
        if ((lane & 15) == 0) atomicAdd(&wsS[c0 + i], s);
    }
}

__global__ void zeroK(float* __restrict__ ws) {
    int i = blockIdx.x * 256 + threadIdx.x;
    if (i < 32896) ws[i] = 0.0f;
}

__global__ void finishK(const float* __restrict__ ws,
                        const float* __restrict__ w_mu, const float* __restrict__ w_cov,
                        const float* __restrict__ w_mu_out, const float* __restrict__ w_cov_out,
                        const float* __restrict__ b_mu, const float* __restrict__ b_cov,
                        float* __restrict__ out, float invN)
{
    const float* Gh  = ws;
    const float* Ghl = ws + 16384;
    const float* S   = ws + 32768;
    __shared__ float lmu[128];
    __shared__ float red[8][6];

    const int tid = threadIdx.x;
    if (tid < 128) lmu[tid] = S[tid] * invN;
    __syncthreads();

    float a0 = 0.f, a1 = 0.f, a2 = 0.f;
    for (int p = tid; p < 16384; p += NTHR) {
        const int e = p >> 7, t = p & 127;
        const float g = (Gh[p] + Ghl[p] + Ghl[t * 128 + e]) * invN - lmu[e] * lmu[t];
        a0 += g * w_cov[3 * p + 0];
        a1 += g * w_cov[3 * p + 1];
        a2 += g * w_cov[3 * p + 2];
    }
    float m0 = 0.f, m1 = 0.f, m2 = 0.f;
    if (tid < 128) {
        const float mv = lmu[tid];
        m0 = mv * w_mu[3 * tid + 0];
        m1 = mv * w_mu[3 * tid + 1];
        m2 = mv * w_mu[3 * tid + 2];
    }
    #pragma unroll
    for (int off = 32; off > 0; off >>= 1) {
        a0 += __shfl_down(a0, off); a1 += __shfl_down(a1, off); a2 += __shfl_down(a2, off);
        m0 += __shfl_down(m0, off); m1 += __shfl_down(m1, off); m2 += __shfl_down(m2, off);
    }
    const int lane = tid & 63, wave = tid >> 6;
    if (lane == 0) {
        red[wave][0] = a0; red[wave][1] = a1; red[wave][2] = a2;
        red[wave][3] = m0; red[wave][4] = m1; red[wave][5] = m2;
    }
    __syncthreads();
    if (tid == 0) {
        float A[6] = {0, 0, 0, 0, 0, 0};
        for (int w = 0; w < 8; ++w)
            for (int q = 0; q < 6; ++q) A[q] += red[w][q];
        float r = 0.f;
        for (int h = 0; h < 3; ++h) {
            float ch = A[h] + b_cov[h];
            float mh = A[3 + h] + b_mu[h];
            ch = fmaxf(ch, 0.2f * ch);   // lrelu, LEAK=0.2
            mh = fmaxf(mh, 0.2f * mh);
            r += mh * w_mu_out[h] + ch * w_cov_out[h];
        }
        out[0] = r;
    }
}

extern "C" void kernel_launch(void* const* d_in, const int* in_sizes, int n_in,
                              void* d_out, int out_size, void* d_ws, size_t ws_size,
                              hipStream_t stream) {
    const float* x         = (const float*)d_in[0];
    const float* w_mu      = (const float*)d_in[1];
    const float* w_cov     = (const float*)d_in[2];
    const float* w_mu_out  = (const float*)d_in[3];
    const float* w_cov_out = (const float*)d_in[4];
    const float* b_mu      = (const float*)d_in[5];
    const float* b_cov     = (const float*)d_in[6];
    float* out = (float*)d_out;
    float* ws  = (float*)d_ws;

    const int N = in_sizes[0] / 128;   // 1,000,000
    const int nchunks = N / BK;        // 15,625 (exact)

    zeroK<<<129, 256, 0, stream>>>(ws);
    mainK<<<GRID, NTHR, 0, stream>>>(x, ws, nchunks);
    finishK<<<1, NTHR, 0, stream>>>(ws, w_mu, w_cov, w_mu_out, w_cov_out,
                                    b_mu, b_cov, out, 1.0f / (float)N);
}